// Round 2
// baseline (1174.929 us; speedup 1.0000x reference)
//
#include <hip/hip_runtime.h>
#include <math.h>

// ---------------------------------------------------------------------------
// PiT: encoder lift -> down pos-att -> 4x (pos-att + MLP + residual) -> up
// pos-att -> decoder. Sparse attention via exact percentile selection.
// All fp32. Tolerance is ~2% relative (threshold = ref_absmax/50).
// ---------------------------------------------------------------------------

__device__ __forceinline__ float gelu_f(float x) {
  // jax.nn.gelu approximate=True: x * 0.5*(1+tanh(sqrt(2/pi)*(x+0.044715 x^3)))
  float x3 = x * x * x;
  float inner = x + 0.044715f * x3;
  float t = tanhf(0.7978845608028654f * inner);
  return x * (0.5f * (1.0f + t));
}

// ---------------- encoder lift: out[m][o] = gelu(x[m]·w[o] + b[o]), K=3 -----
__global__ __launch_bounds__(256) void k_lift(const float* __restrict__ x,
                                              const float* __restrict__ w,
                                              const float* __restrict__ b,
                                              float* __restrict__ out) {
  int gid = blockIdx.x * 256 + threadIdx.x;  // 4*4096*256 total
  int m = gid >> 8, o = gid & 255;
  float a0 = x[m * 3 + 0], a1 = x[m * 3 + 1], a2 = x[m * 3 + 2];
  float acc = a0 * w[o * 3 + 0] + a1 * w[o * 3 + 1] + a2 * w[o * 3 + 2] + b[o];
  out[gid] = gelu_f(acc);
}

// ---------------- dense linear: C = act(A @ W^T + bias [+ D]) ---------------
// A [M][256]; WL=0: W row-major [256][256] (out,in). WL=1: value-projection
// layout w[h][j][k] with out-col c=h*32+k -> W[(c>>5)*8192 + j*32 + (c&31)].
template <int WL, int ACT, int ADDRES>
__global__ __launch_bounds__(256) void k_linear(const float* __restrict__ A,
                                                const float* __restrict__ W,
                                                const float* __restrict__ bias,
                                                const float* __restrict__ D,
                                                float* __restrict__ C, int M) {
  __shared__ __align__(16) float Al[32][68];
  __shared__ __align__(16) float Wl[32][68];
  int t = threadIdx.x;
  int m0 = blockIdx.x * 64, o0 = blockIdx.y * 64;
  int tr = t >> 4, tc = t & 15;
  float acc[4][4] = {{0.0f}};
  for (int kb = 0; kb < 256; kb += 32) {
    // stage A tile: 64 rows x 32 k = 512 float4s, 2 per thread
#pragma unroll
    for (int e = 0; e < 2; ++e) {
      int idx = t + 256 * e;       // 0..511
      int m = idx >> 3;            // 0..63
      int kq = idx & 7;            // 0..7
      float4 v = *(const float4*)(A + (size_t)(m0 + m) * 256 + kb + kq * 4);
      Al[kq * 4 + 0][m] = v.x; Al[kq * 4 + 1][m] = v.y;
      Al[kq * 4 + 2][m] = v.z; Al[kq * 4 + 3][m] = v.w;
    }
    if (WL == 0) {
#pragma unroll
      for (int e = 0; e < 2; ++e) {
        int idx = t + 256 * e;
        int o = idx >> 3;
        int kq = idx & 7;
        float4 v = *(const float4*)(W + (size_t)(o0 + o) * 256 + kb + kq * 4);
        Wl[kq * 4 + 0][o] = v.x; Wl[kq * 4 + 1][o] = v.y;
        Wl[kq * 4 + 2][o] = v.z; Wl[kq * 4 + 3][o] = v.w;
      }
    } else {
#pragma unroll
      for (int e = 0; e < 8; ++e) {
        int idx = t + 256 * e;  // 0..2047
        int k = idx >> 6, o = idx & 63;
        int cc = o0 + o;
        Wl[k][o] = W[(size_t)(cc >> 5) * 8192 + (size_t)(kb + k) * 32 + (cc & 31)];
      }
    }
    __syncthreads();
#pragma unroll
    for (int kk = 0; kk < 32; ++kk) {
      float4 av = *(const float4*)&Al[kk][tr * 4];
      float4 wv = *(const float4*)&Wl[kk][tc * 4];
      float aa[4] = {av.x, av.y, av.z, av.w};
      float ww[4] = {wv.x, wv.y, wv.z, wv.w};
#pragma unroll
      for (int i = 0; i < 4; i++)
#pragma unroll
        for (int jx = 0; jx < 4; jx++)
          acc[i][jx] = fmaf(aa[i], ww[jx], acc[i][jx]);
    }
    __syncthreads();
  }
#pragma unroll
  for (int i = 0; i < 4; i++) {
    int m = m0 + tr * 4 + i;
#pragma unroll
    for (int jx = 0; jx < 4; jx++) {
      int o = o0 + tc * 4 + jx;
      float v = acc[i][jx];
      if (bias) v += bias[o];
      if (ADDRES) v += D[(size_t)m * 256 + o];
      if (ACT) v = gelu_f(v);
      C[(size_t)m * 256 + o] = v;
    }
  }
}

// ---------------- percentile selection + softmax weights per row ------------
// Row of sd = m_dist*scale; keep sd <= thr where thr is the jnp.percentile
// linear interpolation between order stats k_lo, k_lo+1. Emits compacted
// (index, normalized softmax weight) lists.
template <int N, int CAP>
__global__ __launch_bounds__(256) void k_select(const float* __restrict__ mdist,
                                                const float* __restrict__ r,
                                                float idx_q, int Nq, int scap,
                                                int* __restrict__ cnt,
                                                int* __restrict__ kidx,
                                                float* __restrict__ kwts) {
  __shared__ float sd[N];
  __shared__ float cand[CAP];
  __shared__ int scnt;
  __shared__ float sred[4];
  __shared__ int sscan[256];
  int row = blockIdx.x;
  int t = threadIdx.x;
  int h = row / Nq;
  // scale = tan(0.25*pi*(1-1e-7)*(1+sin(r))) with f64-evaluated, f32-rounded
  // transcendentals (ill-conditioned near the tan pole).
  double rd = (double)r[h];
  float s1 = (float)sin(rd);
  float u = 1.0f + s1;
  float vc = (float)(0.7853981633974483 * (1.0 - 1e-7));
  float wf = vc * u;
  float scale = (float)tan((double)wf);

  const float* mrow = mdist + (size_t)row * N;
  float lmin = INFINITY;
  for (int i = t; i < N; i += 256) {
    float v = mrow[i] * scale;
    sd[i] = v;
    lmin = fminf(lmin, v);
  }
#pragma unroll
  for (int off = 32; off > 0; off >>= 1) lmin = fminf(lmin, __shfl_down(lmin, off));
  if ((t & 63) == 0) sred[t >> 6] = lmin;
  __syncthreads();
  float rowmin = fminf(fminf(sred[0], sred[1]), fminf(sred[2], sred[3]));

  // jnp.percentile linear interp: pos = (q/100)*(N-1) in f32
  float pos = __fmul_rn(idx_q, (float)(N - 1));
  float lo = floorf(pos);
  int k_lo = (int)lo;
  float hw = __fsub_rn(pos, lo);
  float lw = __fsub_rn(1.0f, hw);
  int need = k_lo + 2;

  // pivot prefilter: uniform data => expected count ~1.6x need; retry loop
  float p0 = scale * fminf(1.0f, ((float)need + 6.0f * sqrtf((float)need) + 8.0f) / (float)N);
  int count = 0;
  for (int iter = 0; iter < 48; ++iter) {
    __syncthreads();
    if (t == 0) scnt = 0;
    __syncthreads();
    for (int i = t; i < N; i += 256) {
      float v = sd[i];
      if (v <= p0) {
        int p = atomicAdd(&scnt, 1);
        if (p < CAP) cand[p] = v;
      }
    }
    __syncthreads();
    count = scnt;
    if (count >= need && count <= CAP) break;
    if (count < need) p0 = p0 * 1.5f + 1e-37f;
    else p0 = p0 * 0.7f;
  }
  if (count > CAP) count = CAP;
  __syncthreads();
  for (int i = t; i < CAP; i += 256)
    if (i >= count) cand[i] = INFINITY;
  __syncthreads();
  // bitonic sort of CAP candidates (ascending)
  for (int ksz = 2; ksz <= CAP; ksz <<= 1) {
    for (int jj = ksz >> 1; jj > 0; jj >>= 1) {
      for (int i = t; i < CAP; i += 256) {
        int ixj = i ^ jj;
        if (ixj > i) {
          float a = cand[i], bb = cand[ixj];
          bool up = ((i & ksz) == 0);
          if (up ? (a > bb) : (a < bb)) { cand[i] = bb; cand[ixj] = a; }
        }
      }
      __syncthreads();
    }
  }
  float v_lo = cand[k_lo];
  float v_hi = cand[k_lo + 1];
  float thr = __fadd_rn(__fmul_rn(v_lo, lw), __fmul_rn(v_hi, hw));

  // pass B: count kept, exclusive scan for deterministic compaction, sum exp
  int myc = 0;
  float lsum = 0.0f;
  for (int i = t; i < N; i += 256) {
    float v = sd[i];
    if (v <= thr) { myc++; lsum += expf(__fsub_rn(rowmin, v)); }
  }
  sscan[t] = myc;
  __syncthreads();
  for (int off = 1; off < 256; off <<= 1) {
    int vv = (t >= off) ? sscan[t - off] : 0;
    __syncthreads();
    sscan[t] += vv;
    __syncthreads();
  }
  int base = sscan[t] - myc;
  int total_cnt = sscan[255];
#pragma unroll
  for (int off = 32; off > 0; off >>= 1) lsum += __shfl_down(lsum, off);
  __syncthreads();
  if ((t & 63) == 0) sred[t >> 6] = lsum;
  __syncthreads();
  float total = (sred[0] + sred[1]) + (sred[2] + sred[3]);

  int w_off = base;
  size_t obase = (size_t)row * scap;
  for (int i = t; i < N; i += 256) {
    float v = sd[i];
    if (v <= thr) {
      if (w_off < scap) {
        kidx[obase + w_off] = i;
        kwts[obase + w_off] = expf(__fsub_rn(rowmin, v)) / total;
      }
      w_off++;
    }
  }
  if (t == 0) cnt[row] = total_cnt < scap ? total_cnt : scap;
}

// ---------------- sparse PV gather + gelu -----------------------------------
// block = (h,j); 128 threads = (b, k). out[b][j][h*32+k] = gelu(sum_n w*V[b][n][h*32+k])
__global__ __launch_bounds__(128) void k_pv(const float* __restrict__ V,
                                            const int* __restrict__ cnt,
                                            const int* __restrict__ kidx,
                                            const float* __restrict__ kwts,
                                            int scap, float* __restrict__ out,
                                            int Nq, int Nk) {
  __shared__ int sIdx[192];
  __shared__ float sW[192];
  int row = blockIdx.x;
  int h = row / Nq, j = row - h * Nq;
  int t = threadIdx.x;
  int b = t >> 5, k = t & 31;
  int c = cnt[row];
  if (c < 0) c = 0;
  if (c > scap) c = scap;
  if (c > 192) c = 192;
  size_t ib = (size_t)row * scap;
  for (int e = t; e < c; e += 128) { sIdx[e] = kidx[ib + e]; sW[e] = kwts[ib + e]; }
  __syncthreads();
  float acc = 0.0f;
  int col = h * 32 + k;
  for (int e = 0; e < c; ++e) {
    int n = sIdx[e];
    acc = fmaf(sW[e], V[((size_t)b * Nk + n) * 256 + col], acc);
  }
  out[((size_t)b * Nq + j) * 256 + col] = gelu_f(acc);
}

// ---------------- final 256->1 projection -----------------------------------
__global__ __launch_bounds__(256) void k_de2(const float* __restrict__ A,
                                             const float* __restrict__ w,
                                             const float* __restrict__ b,
                                             float* __restrict__ out) {
  int t = threadIdx.x;
  int row = blockIdx.x * 4 + (t >> 6);
  int lane = t & 63;
  const float* ar = A + (size_t)row * 256;
  float s = 0.0f;
  for (int i = lane; i < 256; i += 64) s = fmaf(ar[i], w[i], s);
#pragma unroll
  for (int off = 32; off > 0; off >>= 1) s += __shfl_down(s, off);
  if (lane == 0) out[row] = s + b[0];
}

// ---------------------------------------------------------------------------
extern "C" void kernel_launch(void* const* d_in, const int* in_sizes, int n_in,
                              void* d_out, int out_size, void* d_ws, size_t ws_size,
                              hipStream_t stream) {
  const float* x      = (const float*)d_in[0];
  const float* mdd    = (const float*)d_in[1];
  const float* mdb    = (const float*)d_in[2];
  const float* mdu    = (const float*)d_in[3];
  const float* en_w   = (const float*)d_in[4];
  const float* en_b   = (const float*)d_in[5];
  const float* down_r = (const float*)d_in[6];
  const float* down_w = (const float*)d_in[7];
  const float* pa_r   = (const float*)d_in[8];
  const float* pa_w   = (const float*)d_in[9];
  const float* mlp1_w = (const float*)d_in[10];
  const float* mlp1_b = (const float*)d_in[11];
  const float* mlp2_w = (const float*)d_in[12];
  const float* mlp2_b = (const float*)d_in[13];
  const float* res_w  = (const float*)d_in[14];
  const float* res_b  = (const float*)d_in[15];
  const float* up_r   = (const float*)d_in[16];
  const float* up_w   = (const float*)d_in[17];
  const float* de1_w  = (const float*)d_in[18];
  const float* de1_b  = (const float*)d_in[19];
  const float* de2_w  = (const float*)d_in[20];
  const float* de2_b  = (const float*)d_in[21];
  float* out = (float*)d_out;
  float* ws = (float*)d_ws;

  // ws layout (floats)
  float* hfull = ws;                   // 4*4096*256 = 4194304
  float* val   = ws + 4194304;         // 4194304
  float* paout = ws + 8388608;         // 4194304
  float* hlat  = ws + 12582912;        // 1048576
  float* t1    = ws + 13631488;        // 1048576
  float* t2    = ws + 14680064;        // 1048576
  int*   cnt   = (int*)(ws + 15728640);  // 32768
  int*   kidx  = (int*)(ws + 15761408);  // 2097152
  float* kwts  = ws + 17858560;          // 2097152
  // total ~76 MiB

  // encoder
  k_lift<<<16384, 256, 0, stream>>>(x, en_w, en_b, hfull);

  // down stage (H=8, Nq=1024, Nk=4096, q=3 -> keep 123)
  k_linear<1, 0, 0><<<dim3(256, 4), 256, 0, stream>>>(hfull, down_w, nullptr, nullptr, val, 16384);
  k_select<4096, 512><<<8192, 256, 0, stream>>>(mdd, down_r, (float)(3.0 / 100.0), 1024, 192, cnt, kidx, kwts);
  k_pv<<<8192, 128, 0, stream>>>(val, cnt, kidx, kwts, 192, hlat, 1024, 4096);

  // processor blocks (Nq=Nk=1024, q=5 -> keep 52)
  for (int i = 0; i < 4; i++) {
    k_linear<1, 0, 0><<<dim3(64, 4), 256, 0, stream>>>(hlat, pa_w + (size_t)i * 65536, nullptr, nullptr, val, 4096);
    k_select<1024, 256><<<8192, 256, 0, stream>>>(mdb + (size_t)i * 8388608, pa_r + i * 8, (float)(5.0 / 100.0), 1024, 64, cnt, kidx, kwts);
    k_pv<<<8192, 128, 0, stream>>>(val, cnt, kidx, kwts, 64, paout, 1024, 1024);
    k_linear<0, 1, 0><<<dim3(64, 4), 256, 0, stream>>>(paout, mlp1_w + (size_t)i * 65536, mlp1_b + i * 256, nullptr, t1, 4096);
    k_linear<0, 0, 0><<<dim3(64, 4), 256, 0, stream>>>(hlat, res_w + (size_t)i * 65536, res_b + i * 256, nullptr, t2, 4096);
    k_linear<0, 1, 1><<<dim3(64, 4), 256, 0, stream>>>(t1, mlp2_w + (size_t)i * 65536, mlp2_b + i * 256, t2, hlat, 4096);
  }

  // up stage (H=8, Nq=4096, Nk=1024, q=3 -> keep 31)
  k_linear<1, 0, 0><<<dim3(64, 4), 256, 0, stream>>>(hlat, up_w, nullptr, nullptr, val, 4096);
  k_select<1024, 256><<<32768, 256, 0, stream>>>(mdu, up_r, (float)(3.0 / 100.0), 4096, 64, cnt, kidx, kwts);
  k_pv<<<32768, 128, 0, stream>>>(val, cnt, kidx, kwts, 64, paout, 4096, 1024);

  // decoder
  k_linear<0, 1, 0><<<dim3(256, 4), 256, 0, stream>>>(paout, de1_w, de1_b, nullptr, hfull, 16384);
  k_de2<<<4096, 256, 0, stream>>>(hfull, de2_w, de2_b, out);
}

// Round 3
// 992.854 us; speedup vs baseline: 1.1834x; 1.1834x over previous
//
#include <hip/hip_runtime.h>
#include <math.h>

// ---------------------------------------------------------------------------
// PiT: encoder lift -> down pos-att -> 4x (pos-att + MLP + residual) -> up
// pos-att -> decoder. Sparse attention via exact percentile selection.
// All fp32. Tolerance is ~2% relative (threshold = ref_absmax/50).
// ---------------------------------------------------------------------------

__device__ __forceinline__ float gelu_f(float x) {
  float x3 = x * x * x;
  float inner = x + 0.044715f * x3;
  float t = tanhf(0.7978845608028654f * inner);
  return x * (0.5f * (1.0f + t));
}

// ---------------- encoder lift: out[m][o] = gelu(x[m]·w[o] + b[o]), K=3 -----
__global__ __launch_bounds__(256) void k_lift(const float* __restrict__ x,
                                              const float* __restrict__ w,
                                              const float* __restrict__ b,
                                              float* __restrict__ out) {
  int gid = blockIdx.x * 256 + threadIdx.x;
  int m = gid >> 8, o = gid & 255;
  float a0 = x[m * 3 + 0], a1 = x[m * 3 + 1], a2 = x[m * 3 + 2];
  float acc = a0 * w[o * 3 + 0] + a1 * w[o * 3 + 1] + a2 * w[o * 3 + 2] + b[o];
  out[gid] = gelu_f(acc);
}

// ---------------- dense linear: C = act(A @ W^T + bias [+ D]) ---------------
template <int WL, int ACT, int ADDRES>
__global__ __launch_bounds__(256) void k_linear(const float* __restrict__ A,
                                                const float* __restrict__ W,
                                                const float* __restrict__ bias,
                                                const float* __restrict__ D,
                                                float* __restrict__ C, int M) {
  __shared__ __align__(16) float Al[32][68];
  __shared__ __align__(16) float Wl[32][68];
  int t = threadIdx.x;
  int m0 = blockIdx.x * 64, o0 = blockIdx.y * 64;
  int tr = t >> 4, tc = t & 15;
  float acc[4][4] = {{0.0f}};
  for (int kb = 0; kb < 256; kb += 32) {
#pragma unroll
    for (int e = 0; e < 2; ++e) {
      int idx = t + 256 * e;
      int m = idx >> 3;
      int kq = idx & 7;
      float4 v = *(const float4*)(A + (size_t)(m0 + m) * 256 + kb + kq * 4);
      Al[kq * 4 + 0][m] = v.x; Al[kq * 4 + 1][m] = v.y;
      Al[kq * 4 + 2][m] = v.z; Al[kq * 4 + 3][m] = v.w;
    }
    if (WL == 0) {
#pragma unroll
      for (int e = 0; e < 2; ++e) {
        int idx = t + 256 * e;
        int o = idx >> 3;
        int kq = idx & 7;
        float4 v = *(const float4*)(W + (size_t)(o0 + o) * 256 + kb + kq * 4);
        Wl[kq * 4 + 0][o] = v.x; Wl[kq * 4 + 1][o] = v.y;
        Wl[kq * 4 + 2][o] = v.z; Wl[kq * 4 + 3][o] = v.w;
      }
    } else {
#pragma unroll
      for (int e = 0; e < 8; ++e) {
        int idx = t + 256 * e;
        int k = idx >> 6, o = idx & 63;
        int cc = o0 + o;
        Wl[k][o] = W[(size_t)(cc >> 5) * 8192 + (size_t)(kb + k) * 32 + (cc & 31)];
      }
    }
    __syncthreads();
#pragma unroll
    for (int kk = 0; kk < 32; ++kk) {
      float4 av = *(const float4*)&Al[kk][tr * 4];
      float4 wv = *(const float4*)&Wl[kk][tc * 4];
      float aa[4] = {av.x, av.y, av.z, av.w};
      float ww[4] = {wv.x, wv.y, wv.z, wv.w};
#pragma unroll
      for (int i = 0; i < 4; i++)
#pragma unroll
        for (int jx = 0; jx < 4; jx++)
          acc[i][jx] = fmaf(aa[i], ww[jx], acc[i][jx]);
    }
    __syncthreads();
  }
#pragma unroll
  for (int i = 0; i < 4; i++) {
    int m = m0 + tr * 4 + i;
#pragma unroll
    for (int jx = 0; jx < 4; jx++) {
      int o = o0 + tc * 4 + jx;
      float v = acc[i][jx];
      if (bias) v += bias[o];
      if (ADDRES) v += D[(size_t)m * 256 + o];
      if (ACT) v = gelu_f(v);
      C[(size_t)m * 256 + o] = v;
    }
  }
}

// ---------------- precompute the 48 attention scales -------------------------
// scale = tan(0.25*pi*(1-1e-7)*(1+sin(r))), f64-evaluated transcendentals,
// f32-rounded intermediates exactly as the (verified bit-exact) r2 kernel.
__global__ void k_scales(const float* __restrict__ down_r,
                         const float* __restrict__ pa_r,
                         const float* __restrict__ up_r,
                         float* __restrict__ scales) {
  int t = threadIdx.x;
  if (t >= 48) return;
  float rv;
  if (t < 8) rv = down_r[t];
  else if (t < 40) rv = pa_r[t - 8];
  else rv = up_r[t - 40];
  double rd = (double)rv;
  float s1 = (float)sin(rd);
  float u = 1.0f + s1;
  float vc = (float)(0.7853981633974483 * (1.0 - 1e-7));
  float wf = vc * u;
  scales[t] = (float)tan((double)wf);
}

// ---------------- percentile selection + softmax weights per row ------------
// Raw-domain candidate gather (rank-equivalent since scale>0), hybrid
// wave-register + LDS bitonic sort of 256 candidates, threshold and softmax
// computed on f32-rounded products (bit-identical to reference semantics).
__device__ __forceinline__ void ldsExchange(volatile float* cv, volatile int* ci,
                                            int t, int j) {
  if ((t & j) == 0) {  // ascending (k>=256 context)
    int p = t + j;
    float a = cv[t], b = cv[p];
    if (b < a) {
      int ia = ci[t], ib = ci[p];
      cv[t] = b; cv[p] = a; ci[t] = ib; ci[p] = ia;
    }
  }
  __syncthreads();
}

template <int N>
__global__ __launch_bounds__(256) void k_select2(const float* __restrict__ mdist,
                                                 const float* __restrict__ scales,
                                                 int sc_off, int Nq, int k_lo,
                                                 float hw, float lw, float praw0,
                                                 int need, int scap,
                                                 int* __restrict__ cnt,
                                                 int* __restrict__ kidx,
                                                 float* __restrict__ kwts) {
  __shared__ float cv[256];
  __shared__ int ci[256];
  __shared__ int scnt;
  __shared__ float sred[4];
  __shared__ int swk[4];
  int row = blockIdx.x;
  int t = threadIdx.x;
  int h = row / Nq;
  float scale = scales[sc_off + h];
  const float* mrow = mdist + (size_t)row * N;

  float praw = praw0;
  for (int iter = 0; iter < 32; ++iter) {
    __syncthreads();
    if (t == 0) scnt = 0;
    __syncthreads();
    for (int i = t; i < N; i += 256) {
      float m = mrow[i];
      if (m <= praw) {
        int p = atomicAdd(&scnt, 1);
        if (p < 256) { cv[p] = m; ci[p] = i; }
      }
    }
    __syncthreads();
    int count = scnt;
    bool bad_lo = count < need, bad_hi = count > 256;
    if ((bad_lo || bad_hi) && iter < 24) {
      praw = bad_lo ? praw * 1.5f : praw * 0.7f;
      continue;
    }
    if (count > 256) count = 256;

    // ---- sort 256 (value,index) ascending: wave bitonic-64 + LDS merges ----
    float v = (t < count) ? cv[t] : INFINITY;
    int id = (t < count) ? ci[t] : 0;
#pragma unroll
    for (int k = 2; k <= 64; k <<= 1) {
#pragma unroll
      for (int j = k >> 1; j > 0; j >>= 1) {
        float pv = __shfl_xor(v, j);
        int pi = __shfl_xor(id, j);
        bool takeMin = (((t & k) == 0) == ((t & j) == 0));
        bool sw = takeMin ? (pv < v) : (pv > v);
        if (sw) { v = pv; id = pi; }
      }
    }
    cv[t] = v; ci[t] = id;
    __syncthreads();
    // k = 128 stage: j=64 via LDS (dir by t&128), then j<=32 in regs
    {
      if ((t & 64) == 0) {
        int p = t + 64;
        bool up = ((t & 128) == 0);
        float a = cv[t], b = cv[p];
        bool sw = up ? (b < a) : (b > a);
        if (sw) { int ia = ci[t], ib = ci[p]; cv[t] = b; cv[p] = a; ci[t] = ib; ci[p] = ia; }
      }
      __syncthreads();
      v = cv[t]; id = ci[t];
#pragma unroll
      for (int j = 32; j > 0; j >>= 1) {
        float pv = __shfl_xor(v, j);
        int pi = __shfl_xor(id, j);
        bool takeMin = (((t & 128) == 0) == ((t & j) == 0));
        bool sw = takeMin ? (pv < v) : (pv > v);
        if (sw) { v = pv; id = pi; }
      }
      cv[t] = v; ci[t] = id;
      __syncthreads();
    }
    // k = 256 stage: j=128,64 via LDS (ascending), then j<=32 in regs
    ldsExchange(cv, ci, t, 128);
    ldsExchange(cv, ci, t, 64);
    v = cv[t]; id = ci[t];
#pragma unroll
    for (int j = 32; j > 0; j >>= 1) {
      float pv = __shfl_xor(v, j);
      int pi = __shfl_xor(id, j);
      bool takeMin = ((t & j) == 0);
      bool sw = takeMin ? (pv < v) : (pv > v);
      if (sw) { v = pv; id = pi; }
    }
    cv[t] = v; ci[t] = id;
    __syncthreads();

    // ---- threshold on rounded products (reference-exact formula) ----
    float vlo = __fmul_rn(cv[k_lo], scale);
    float vhi = __fmul_rn(cv[k_lo + 1], scale);
    float thr = __fadd_rn(__fmul_rn(vlo, lw), __fmul_rn(vhi, hw));
    // safety: every element <= thr (in product domain) must be a candidate
    if (__fmul_rn(praw, scale) <= thr && iter < 24) {
      praw = praw * 1.25f;
      continue;
    }

    // ---- kept = prefix of sorted candidates (rounding is monotone) ----
    float sdv = __fmul_rn(v, scale);  // inf for padding
    bool kept = (sdv <= thr);
    unsigned long long bal = __ballot(kept);
    if ((t & 63) == 0) swk[t >> 6] = (int)__popcll(bal);
    __syncthreads();
    int K = swk[0] + swk[1] + swk[2] + swk[3];

    float v0s = __fmul_rn(cv[0], scale);  // row min of sd (always kept)
    float e0 = 0.0f;
    if (t < K) e0 = expf(__fsub_rn(v0s, sdv));
    float e = e0;
#pragma unroll
    for (int off = 32; off > 0; off >>= 1) e += __shfl_down(e, off);
    if ((t & 63) == 0) sred[t >> 6] = e;
    __syncthreads();
    float total = (sred[0] + sred[1]) + (sred[2] + sred[3]);

    if (t < K && t < scap) {
      kidx[(size_t)row * scap + t] = id;
      kwts[(size_t)row * scap + t] = e0 / total;
    }
    if (t == 0) cnt[row] = (K < scap) ? K : scap;
    return;
  }
}

// ---------------- sparse PV gather + gelu -----------------------------------
__global__ __launch_bounds__(128) void k_pv(const float* __restrict__ V,
                                            const int* __restrict__ cnt,
                                            const int* __restrict__ kidx,
                                            const float* __restrict__ kwts,
                                            int scap, float* __restrict__ out,
                                            int Nq, int Nk) {
  __shared__ int sIdx[192];
  __shared__ float sW[192];
  int row = blockIdx.x;
  int h = row / Nq, j = row - h * Nq;
  int t = threadIdx.x;
  int b = t >> 5, k = t & 31;
  int c = cnt[row];
  if (c < 0) c = 0;
  if (c > scap) c = scap;
  if (c > 192) c = 192;
  size_t ib = (size_t)row * scap;
  for (int e = t; e < c; e += 128) { sIdx[e] = kidx[ib + e]; sW[e] = kwts[ib + e]; }
  __syncthreads();
  float acc = 0.0f;
  int col = h * 32 + k;
  for (int e = 0; e < c; ++e) {
    int n = sIdx[e];
    acc = fmaf(sW[e], V[((size_t)b * Nk + n) * 256 + col], acc);
  }
  out[((size_t)b * Nq + j) * 256 + col] = gelu_f(acc);
}

// ---------------- final 256->1 projection -----------------------------------
__global__ __launch_bounds__(256) void k_de2(const float* __restrict__ A,
                                             const float* __restrict__ w,
                                             const float* __restrict__ b,
                                             float* __restrict__ out) {
  int t = threadIdx.x;
  int row = blockIdx.x * 4 + (t >> 6);
  int lane = t & 63;
  const float* ar = A + (size_t)row * 256;
  float s = 0.0f;
  for (int i = lane; i < 256; i += 64) s = fmaf(ar[i], w[i], s);
#pragma unroll
  for (int off = 32; off > 0; off >>= 1) s += __shfl_down(s, off);
  if (lane == 0) out[row] = s + b[0];
}

// ---------------------------------------------------------------------------
struct SelParams { int k_lo; float hw, lw, praw0; int need; };
static SelParams sel_params(double q, int N) {
  SelParams p;
  float idx_q = (float)(q / 100.0);
  float pos = idx_q * (float)(N - 1);
  float lo = floorf(pos);
  p.k_lo = (int)lo;
  p.hw = pos - lo;
  p.lw = 1.0f - p.hw;
  p.need = p.k_lo + 2;
  p.praw0 = ((float)p.need + 6.0f * sqrtf((float)p.need) + 8.0f) / (float)N;
  return p;
}

extern "C" void kernel_launch(void* const* d_in, const int* in_sizes, int n_in,
                              void* d_out, int out_size, void* d_ws, size_t ws_size,
                              hipStream_t stream) {
  const float* x      = (const float*)d_in[0];
  const float* mdd    = (const float*)d_in[1];
  const float* mdb    = (const float*)d_in[2];
  const float* mdu    = (const float*)d_in[3];
  const float* en_w   = (const float*)d_in[4];
  const float* en_b   = (const float*)d_in[5];
  const float* down_r = (const float*)d_in[6];
  const float* down_w = (const float*)d_in[7];
  const float* pa_r   = (const float*)d_in[8];
  const float* pa_w   = (const float*)d_in[9];
  const float* mlp1_w = (const float*)d_in[10];
  const float* mlp1_b = (const float*)d_in[11];
  const float* mlp2_w = (const float*)d_in[12];
  const float* mlp2_b = (const float*)d_in[13];
  const float* res_w  = (const float*)d_in[14];
  const float* res_b  = (const float*)d_in[15];
  const float* up_r   = (const float*)d_in[16];
  const float* up_w   = (const float*)d_in[17];
  const float* de1_w  = (const float*)d_in[18];
  const float* de1_b  = (const float*)d_in[19];
  const float* de2_w  = (const float*)d_in[20];
  const float* de2_b  = (const float*)d_in[21];
  float* out = (float*)d_out;
  float* ws = (float*)d_ws;

  // ws layout (floats)
  float* hfull = ws;                     // 4194304
  float* val   = ws + 4194304;           // 4194304
  float* paout = ws + 8388608;           // 4194304
  float* hlat  = ws + 12582912;          // 1048576
  float* t1    = ws + 13631488;          // 1048576
  float* t2    = ws + 14680064;          // 1048576
  int*   cnt   = (int*)(ws + 15728640);  // 32768
  int*   kidx  = (int*)(ws + 15761408);  // 2097152
  float* kwts  = ws + 17858560;          // 2097152
  float* scales = ws + 19955712;         // 48

  k_scales<<<1, 64, 0, stream>>>(down_r, pa_r, up_r, scales);

  // encoder
  k_lift<<<16384, 256, 0, stream>>>(x, en_w, en_b, hfull);

  // down stage (H=8, Nq=1024, Nk=4096, q=3 -> keep ~123)
  SelParams pd = sel_params(3.0, 4096);
  k_linear<1, 0, 0><<<dim3(256, 4), 256, 0, stream>>>(hfull, down_w, nullptr, nullptr, val, 16384);
  k_select2<4096><<<8192, 256, 0, stream>>>(mdd, scales, 0, 1024, pd.k_lo, pd.hw, pd.lw, pd.praw0, pd.need, 192, cnt, kidx, kwts);
  k_pv<<<8192, 128, 0, stream>>>(val, cnt, kidx, kwts, 192, hlat, 1024, 4096);

  // processor blocks (Nq=Nk=1024, q=5 -> keep ~52)
  SelParams pb = sel_params(5.0, 1024);
  for (int i = 0; i < 4; i++) {
    k_linear<1, 0, 0><<<dim3(64, 4), 256, 0, stream>>>(hlat, pa_w + (size_t)i * 65536, nullptr, nullptr, val, 4096);
    k_select2<1024><<<8192, 256, 0, stream>>>(mdb + (size_t)i * 8388608, scales, 8 + i * 8, 1024, pb.k_lo, pb.hw, pb.lw, pb.praw0, pb.need, 64, cnt, kidx, kwts);
    k_pv<<<8192, 128, 0, stream>>>(val, cnt, kidx, kwts, 64, paout, 1024, 1024);
    k_linear<0, 1, 0><<<dim3(64, 4), 256, 0, stream>>>(paout, mlp1_w + (size_t)i * 65536, mlp1_b + i * 256, nullptr, t1, 4096);
    k_linear<0, 0, 0><<<dim3(64, 4), 256, 0, stream>>>(hlat, res_w + (size_t)i * 65536, res_b + i * 256, nullptr, t2, 4096);
    k_linear<0, 1, 1><<<dim3(64, 4), 256, 0, stream>>>(t1, mlp2_w + (size_t)i * 65536, mlp2_b + i * 256, t2, hlat, 4096);
  }

  // up stage (H=8, Nq=4096, Nk=1024, q=3 -> keep ~31)
  SelParams pu = sel_params(3.0, 1024);
  k_linear<1, 0, 0><<<dim3(64, 4), 256, 0, stream>>>(hlat, up_w, nullptr, nullptr, val, 4096);
  k_select2<1024><<<32768, 256, 0, stream>>>(mdu, scales, 40, 4096, pu.k_lo, pu.hw, pu.lw, pu.praw0, pu.need, 64, cnt, kidx, kwts);
  k_pv<<<32768, 128, 0, stream>>>(val, cnt, kidx, kwts, 64, paout, 4096, 1024);

  // decoder
  k_linear<0, 1, 0><<<dim3(256, 4), 256, 0, stream>>>(paout, de1_w, de1_b, nullptr, hfull, 16384);
  k_de2<<<4096, 256, 0, stream>>>(hfull, de2_w, de2_b, out);
}

// Round 4
// 877.588 us; speedup vs baseline: 1.3388x; 1.1313x over previous
//
#include <hip/hip_runtime.h>
#include <math.h>

// ---------------------------------------------------------------------------
// PiT: encoder lift -> down pos-att -> 4x (pos-att + MLP + residual) -> up
// pos-att -> decoder. Sparse attention via exact percentile selection
// (histogram/counting-based order statistics, no sort).
// ---------------------------------------------------------------------------

__device__ __forceinline__ float gelu_f(float x) {
  float x3 = x * x * x;
  float inner = x + 0.044715f * x3;
  float t = tanhf(0.7978845608028654f * inner);
  return x * (0.5f * (1.0f + t));
}

// ---------------- encoder lift: out[m][o] = gelu(x[m]·w[o] + b[o]), K=3 -----
__global__ __launch_bounds__(256) void k_lift(const float* __restrict__ x,
                                              const float* __restrict__ w,
                                              const float* __restrict__ b,
                                              float* __restrict__ out) {
  int gid = blockIdx.x * 256 + threadIdx.x;
  int m = gid >> 8, o = gid & 255;
  float a0 = x[m * 3 + 0], a1 = x[m * 3 + 1], a2 = x[m * 3 + 2];
  float acc = a0 * w[o * 3 + 0] + a1 * w[o * 3 + 1] + a2 * w[o * 3 + 2] + b[o];
  out[gid] = gelu_f(acc);
}

// ---------------- dense linear: C = act(A @ W^T + bias [+ D]) ---------------
template <int WL, int ACT, int ADDRES>
__global__ __launch_bounds__(256) void k_linear(const float* __restrict__ A,
                                                const float* __restrict__ W,
                                                const float* __restrict__ bias,
                                                const float* __restrict__ D,
                                                float* __restrict__ C, int M) {
  __shared__ __align__(16) float Al[32][68];
  __shared__ __align__(16) float Wl[32][68];
  int t = threadIdx.x;
  int m0 = blockIdx.x * 64, o0 = blockIdx.y * 64;
  int tr = t >> 4, tc = t & 15;
  float acc[4][4] = {{0.0f}};
  for (int kb = 0; kb < 256; kb += 32) {
#pragma unroll
    for (int e = 0; e < 2; ++e) {
      int idx = t + 256 * e;
      int m = idx >> 3;
      int kq = idx & 7;
      float4 v = *(const float4*)(A + (size_t)(m0 + m) * 256 + kb + kq * 4);
      Al[kq * 4 + 0][m] = v.x; Al[kq * 4 + 1][m] = v.y;
      Al[kq * 4 + 2][m] = v.z; Al[kq * 4 + 3][m] = v.w;
    }
    if (WL == 0) {
#pragma unroll
      for (int e = 0; e < 2; ++e) {
        int idx = t + 256 * e;
        int o = idx >> 3;
        int kq = idx & 7;
        float4 v = *(const float4*)(W + (size_t)(o0 + o) * 256 + kb + kq * 4);
        Wl[kq * 4 + 0][o] = v.x; Wl[kq * 4 + 1][o] = v.y;
        Wl[kq * 4 + 2][o] = v.z; Wl[kq * 4 + 3][o] = v.w;
      }
    } else {
#pragma unroll
      for (int e = 0; e < 8; ++e) {
        int idx = t + 256 * e;
        int k = idx >> 6, o = idx & 63;
        int cc = o0 + o;
        Wl[k][o] = W[(size_t)(cc >> 5) * 8192 + (size_t)(kb + k) * 32 + (cc & 31)];
      }
    }
    __syncthreads();
#pragma unroll
    for (int kk = 0; kk < 32; ++kk) {
      float4 av = *(const float4*)&Al[kk][tr * 4];
      float4 wv = *(const float4*)&Wl[kk][tc * 4];
      float aa[4] = {av.x, av.y, av.z, av.w};
      float ww[4] = {wv.x, wv.y, wv.z, wv.w};
#pragma unroll
      for (int i = 0; i < 4; i++)
#pragma unroll
        for (int jx = 0; jx < 4; jx++)
          acc[i][jx] = fmaf(aa[i], ww[jx], acc[i][jx]);
    }
    __syncthreads();
  }
#pragma unroll
  for (int i = 0; i < 4; i++) {
    int m = m0 + tr * 4 + i;
#pragma unroll
    for (int jx = 0; jx < 4; jx++) {
      int o = o0 + tc * 4 + jx;
      float v = acc[i][jx];
      if (bias) v += bias[o];
      if (ADDRES) v += D[(size_t)m * 256 + o];
      if (ACT) v = gelu_f(v);
      C[(size_t)m * 256 + o] = v;
    }
  }
}

// ---------------- precompute the 48 attention scales ------------------------
__global__ void k_scales(const float* __restrict__ down_r,
                         const float* __restrict__ pa_r,
                         const float* __restrict__ up_r,
                         float* __restrict__ scales) {
  int t = threadIdx.x;
  if (t >= 48) return;
  float rv;
  if (t < 8) rv = down_r[t];
  else if (t < 40) rv = pa_r[t - 8];
  else rv = up_r[t - 40];
  double rd = (double)rv;
  float s1 = (float)sin(rd);
  float u = 1.0f + s1;
  float vc = (float)(0.7853981633974483 * (1.0 - 1e-7));
  float wf = vc * u;
  scales[t] = (float)tan((double)wf);
}

// ---------------- percentile selection + softmax weights per row ------------
// One global read per row (row cached in LDS). Order stats k_lo, k_lo+1 via
// 256-bin histogram + counting selection (exact, tie-safe, deterministic).
// Threshold/softmax on f32-rounded products: bit-identical to the verified
// r2 semantics (raw-domain ranks are valid since scale>0 and rn is monotone).
template <int N>
__global__ __launch_bounds__(256) void k_select3(
    const float* __restrict__ mdist, const float* __restrict__ scales,
    int sc_off, int Nq, int k_lo, float hw, float lw, int scap,
    int* __restrict__ cnt, int* __restrict__ kidx, float* __restrict__ kwts) {
  constexpr int NPT = N / 256;
  __shared__ __align__(16) float srow[N];
  __shared__ int hist[256];
  __shared__ float sredf[8];
  __shared__ int swoff[4];
  __shared__ int sbinlo, sbinhi, sibase, sincl, sgc;
  __shared__ float scand[128];
  __shared__ float svsel[2];

  int row = blockIdx.x;
  int t = threadIdx.x;
  int wid = t >> 6, lane = t & 63;
  float scale = scales[sc_off + row / Nq];
  const float* mrow = mdist + (size_t)row * N;

  // load row into LDS (float4), track min/max
  float lmin = INFINITY, lmax = -INFINITY;
#pragma unroll
  for (int e = 0; e < NPT / 4; ++e) {
    int i4 = t + 256 * e;
    float4 v = ((const float4*)mrow)[i4];
    ((float4*)srow)[i4] = v;
    lmin = fminf(lmin, fminf(fminf(v.x, v.y), fminf(v.z, v.w)));
    lmax = fmaxf(lmax, fmaxf(fmaxf(v.x, v.y), fmaxf(v.z, v.w)));
  }
#pragma unroll
  for (int off = 32; off > 0; off >>= 1) {
    lmin = fminf(lmin, __shfl_xor(lmin, off));
    lmax = fmaxf(lmax, __shfl_xor(lmax, off));
  }
  if (lane == 0) { sredf[wid] = lmin; sredf[4 + wid] = lmax; }
  __syncthreads();
  float rmin = fminf(fminf(sredf[0], sredf[1]), fminf(sredf[2], sredf[3]));
  float rmax = fmaxf(fmaxf(sredf[4], sredf[5]), fmaxf(sredf[6], sredf[7]));

  float rlo = rmin;
  float rhi = rmax + fmaxf(fabsf(rmax) * 1e-6f, 1e-30f);
  float v_lo = rmin, v_hi = rmin;  // exact fallback for all-equal rows

  for (int it = 0; it < 8; ++it) {
    // exact rank of rlo: r = k_lo - #(v < rlo); also zero hist this phase
    int lbelow = 0;
#pragma unroll
    for (int e = 0; e < NPT; ++e) lbelow += (srow[t + 256 * e] < rlo) ? 1 : 0;
#pragma unroll
    for (int off = 32; off > 0; off >>= 1) lbelow += __shfl_xor(lbelow, off);
    hist[t] = 0;
    if (lane == 0) swoff[wid] = lbelow;
    __syncthreads();
    int below = swoff[0] + swoff[1] + swoff[2] + swoff[3];
    int r = k_lo - below;  // rank within [rlo, rhi)
    float width = rhi - rlo;
    float sinv = 256.0f / width;
    // histogram of in-range values
#pragma unroll
    for (int e = 0; e < NPT; ++e) {
      float v = srow[t + 256 * e];
      if (v >= rlo && v < rhi) {
        int b = (int)((v - rlo) * sinv);
        b = b < 0 ? 0 : (b > 255 ? 255 : b);
        atomicAdd(&hist[b], 1);
      }
    }
    __syncthreads();
    // exclusive scan of hist over 256 bins (wave shfl + LDS combine)
    int c = hist[t];
    int x = c;
#pragma unroll
    for (int off = 1; off < 64; off <<= 1) {
      int y = __shfl_up(x, off);
      if (lane >= off) x += y;
    }
    if (lane == 63) swoff[wid] = x;
    __syncthreads();
    int wo = 0;
#pragma unroll
    for (int w = 0; w < 4; ++w) wo += (w < wid) ? swoff[w] : 0;
    int incl = x + wo;
    int excl = incl - c;
    if (excl <= r && r < incl) { sbinlo = t; sibase = excl; }
    if (excl <= r + 1 && r + 1 < incl) { sbinhi = t; sincl = incl; }
    if (t == 0) sgc = 0;
    __syncthreads();
    int b_lo = sbinlo, b_hi = sbinhi;
    int base = sibase;
    int gcount = sincl - base;
    if (gcount <= 128) {
      // gather candidate values (order-free; dedup-safe counting selection)
#pragma unroll
      for (int e = 0; e < NPT; ++e) {
        float v = srow[t + 256 * e];
        if (v >= rlo && v < rhi) {
          int b = (int)((v - rlo) * sinv);
          b = b < 0 ? 0 : (b > 255 ? 255 : b);
          if (b >= b_lo && b <= b_hi) {
            int p = atomicAdd(&sgc, 1);
            if (p < 128) scand[p] = v;
          }
        }
      }
      __syncthreads();
      int rr = r - base;
      if (t < gcount) {
        float xv = scand[t];
        int clt = 0, ceq = 0;
        for (int j = 0; j < gcount; ++j) {
          float y = scand[j];
          clt += (y < xv) ? 1 : 0;
          ceq += (y == xv) ? 1 : 0;
        }
        if (clt <= rr && rr < clt + ceq) svsel[0] = xv;
        if (clt <= rr + 1 && rr + 1 < clt + ceq) svsel[1] = xv;
      }
      __syncthreads();
      v_lo = svsel[0];
      v_hi = svsel[1];
      break;
    }
    // refine range conservatively (half-bin margins; ranks recounted fresh)
    float w256 = width * (1.0f / 256.0f);
    float nlo = rlo + ((float)b_lo - 0.5f) * w256;
    float nhi = rlo + ((float)b_hi + 1.5f) * w256;
    rlo = fmaxf(rlo, nlo);
    rhi = fminf(rhi, nhi);
    __syncthreads();
  }

  // threshold on rounded products (reference-exact formula)
  float vlos = __fmul_rn(v_lo, scale);
  float vhis = __fmul_rn(v_hi, scale);
  float thr = __fadd_rn(__fmul_rn(vlos, lw), __fmul_rn(vhis, hw));
  float rmins = __fmul_rn(rmin, scale);

  // kept count + exp-sum per thread
  int myc = 0;
  float lsum = 0.0f;
#pragma unroll
  for (int e = 0; e < NPT; ++e) {
    float sdv = __fmul_rn(srow[t + 256 * e], scale);
    if (sdv <= thr) { myc++; lsum += expf(__fsub_rn(rmins, sdv)); }
  }
  int xs = myc;
#pragma unroll
  for (int off = 1; off < 64; off <<= 1) {
    int y = __shfl_up(xs, off);
    if (lane >= off) xs += y;
  }
#pragma unroll
  for (int off = 32; off > 0; off >>= 1) lsum += __shfl_xor(lsum, off);
  if (lane == 63) swoff[wid] = xs;
  if (lane == 0) sredf[wid] = lsum;
  __syncthreads();
  int wo2 = 0;
#pragma unroll
  for (int w = 0; w < 4; ++w) wo2 += (w < wid) ? swoff[w] : 0;
  int mybase = wo2 + xs - myc;
  int K = swoff[0] + swoff[1] + swoff[2] + swoff[3];
  float total = (sredf[0] + sredf[1]) + (sredf[2] + sredf[3]);

  size_t ob = (size_t)row * scap;
  int p = mybase;
#pragma unroll
  for (int e = 0; e < NPT; ++e) {
    int i = t + 256 * e;
    float sdv = __fmul_rn(srow[i], scale);
    if (sdv <= thr) {
      if (p < scap) {
        kidx[ob + p] = i;
        kwts[ob + p] = expf(__fsub_rn(rmins, sdv)) / total;
      }
      p++;
    }
  }
  if (t == 0) cnt[row] = K < scap ? K : scap;
}

// ---------------- sparse PV gather + gelu -----------------------------------
__global__ __launch_bounds__(128) void k_pv(const float* __restrict__ V,
                                            const int* __restrict__ cnt,
                                            const int* __restrict__ kidx,
                                            const float* __restrict__ kwts,
                                            int scap, float* __restrict__ out,
                                            int Nq, int Nk) {
  __shared__ int sIdx[192];
  __shared__ float sW[192];
  int row = blockIdx.x;
  int h = row / Nq, j = row - h * Nq;
  int t = threadIdx.x;
  int b = t >> 5, k = t & 31;
  int c = cnt[row];
  if (c < 0) c = 0;
  if (c > scap) c = scap;
  if (c > 192) c = 192;
  size_t ib = (size_t)row * scap;
  for (int e = t; e < c; e += 128) { sIdx[e] = kidx[ib + e]; sW[e] = kwts[ib + e]; }
  __syncthreads();
  float acc = 0.0f;
  int col = h * 32 + k;
  for (int e = 0; e < c; ++e) {
    int n = sIdx[e];
    acc = fmaf(sW[e], V[((size_t)b * Nk + n) * 256 + col], acc);
  }
  out[((size_t)b * Nq + j) * 256 + col] = gelu_f(acc);
}

// ---------------- final 256->1 projection -----------------------------------
__global__ __launch_bounds__(256) void k_de2(const float* __restrict__ A,
                                             const float* __restrict__ w,
                                             const float* __restrict__ b,
                                             float* __restrict__ out) {
  int t = threadIdx.x;
  int row = blockIdx.x * 4 + (t >> 6);
  int lane = t & 63;
  const float* ar = A + (size_t)row * 256;
  float s = 0.0f;
  for (int i = lane; i < 256; i += 64) s = fmaf(ar[i], w[i], s);
#pragma unroll
  for (int off = 32; off > 0; off >>= 1) s += __shfl_down(s, off);
  if (lane == 0) out[row] = s + b[0];
}

// ---------------------------------------------------------------------------
struct SelParams { int k_lo; float hw, lw; };
static SelParams sel_params(double q, int N) {
  SelParams p;
  float idx_q = (float)(q / 100.0);
  float pos = idx_q * (float)(N - 1);
  float lo = floorf(pos);
  p.k_lo = (int)lo;
  p.hw = pos - lo;
  p.lw = 1.0f - p.hw;
  return p;
}

extern "C" void kernel_launch(void* const* d_in, const int* in_sizes, int n_in,
                              void* d_out, int out_size, void* d_ws, size_t ws_size,
                              hipStream_t stream) {
  const float* x      = (const float*)d_in[0];
  const float* mdd    = (const float*)d_in[1];
  const float* mdb    = (const float*)d_in[2];
  const float* mdu    = (const float*)d_in[3];
  const float* en_w   = (const float*)d_in[4];
  const float* en_b   = (const float*)d_in[5];
  const float* down_r = (const float*)d_in[6];
  const float* down_w = (const float*)d_in[7];
  const float* pa_r   = (const float*)d_in[8];
  const float* pa_w   = (const float*)d_in[9];
  const float* mlp1_w = (const float*)d_in[10];
  const float* mlp1_b = (const float*)d_in[11];
  const float* mlp2_w = (const float*)d_in[12];
  const float* mlp2_b = (const float*)d_in[13];
  const float* res_w  = (const float*)d_in[14];
  const float* res_b  = (const float*)d_in[15];
  const float* up_r   = (const float*)d_in[16];
  const float* up_w   = (const float*)d_in[17];
  const float* de1_w  = (const float*)d_in[18];
  const float* de1_b  = (const float*)d_in[19];
  const float* de2_w  = (const float*)d_in[20];
  const float* de2_b  = (const float*)d_in[21];
  float* out = (float*)d_out;
  float* ws = (float*)d_ws;

  // ws layout (floats)
  float* hfull = ws;                     // 4194304
  float* val   = ws + 4194304;           // 4194304
  float* paout = ws + 8388608;           // 4194304
  float* hlat  = ws + 12582912;          // 1048576
  float* t1    = ws + 13631488;          // 1048576
  float* t2    = ws + 14680064;          // 1048576
  int*   cnt   = (int*)(ws + 15728640);  // 32768
  int*   kidx  = (int*)(ws + 15761408);  // 2097152
  float* kwts  = ws + 17858560;          // 2097152
  float* scales = ws + 19955712;         // 48

  k_scales<<<1, 64, 0, stream>>>(down_r, pa_r, up_r, scales);

  // encoder
  k_lift<<<16384, 256, 0, stream>>>(x, en_w, en_b, hfull);

  // down stage (H=8, Nq=1024, Nk=4096, q=3 -> keep ~123)
  SelParams pd = sel_params(3.0, 4096);
  k_linear<1, 0, 0><<<dim3(256, 4), 256, 0, stream>>>(hfull, down_w, nullptr, nullptr, val, 16384);
  k_select3<4096><<<8192, 256, 0, stream>>>(mdd, scales, 0, 1024, pd.k_lo, pd.hw, pd.lw, 192, cnt, kidx, kwts);
  k_pv<<<8192, 128, 0, stream>>>(val, cnt, kidx, kwts, 192, hlat, 1024, 4096);

  // processor blocks (Nq=Nk=1024, q=5 -> keep ~52)
  SelParams pb = sel_params(5.0, 1024);
  for (int i = 0; i < 4; i++) {
    k_linear<1, 0, 0><<<dim3(64, 4), 256, 0, stream>>>(hlat, pa_w + (size_t)i * 65536, nullptr, nullptr, val, 4096);
    k_select3<1024><<<8192, 256, 0, stream>>>(mdb + (size_t)i * 8388608, scales, 8 + i * 8, 1024, pb.k_lo, pb.hw, pb.lw, 64, cnt, kidx, kwts);
    k_pv<<<8192, 128, 0, stream>>>(val, cnt, kidx, kwts, 64, paout, 1024, 1024);
    k_linear<0, 1, 0><<<dim3(64, 4), 256, 0, stream>>>(paout, mlp1_w + (size_t)i * 65536, mlp1_b + i * 256, nullptr, t1, 4096);
    k_linear<0, 0, 0><<<dim3(64, 4), 256, 0, stream>>>(hlat, res_w + (size_t)i * 65536, res_b + i * 256, nullptr, t2, 4096);
    k_linear<0, 1, 1><<<dim3(64, 4), 256, 0, stream>>>(t1, mlp2_w + (size_t)i * 65536, mlp2_b + i * 256, t2, hlat, 4096);
  }

  // up stage (H=8, Nq=4096, Nk=1024, q=3 -> keep ~31)
  SelParams pu = sel_params(3.0, 1024);
  k_linear<1, 0, 0><<<dim3(64, 4), 256, 0, stream>>>(hlat, up_w, nullptr, nullptr, val, 4096);
  k_select3<1024><<<32768, 256, 0, stream>>>(mdu, scales, 40, 4096, pu.k_lo, pu.hw, pu.lw, 64, cnt, kidx, kwts);
  k_pv<<<32768, 128, 0, stream>>>(val, cnt, kidx, kwts, 64, paout, 4096, 1024);

  // decoder
  k_linear<0, 1, 0><<<dim3(256, 4), 256, 0, stream>>>(paout, de1_w, de1_b, nullptr, hfull, 16384);
  k_de2<<<4096, 256, 0, stream>>>(hfull, de2_w, de2_b, out);
}